// Round 10
// baseline (176.140 us; speedup 1.0000x reference)
//
#include <hip/hip_runtime.h>
#include <hip/hip_bf16.h>

typedef __bf16 bf16_t;
typedef __attribute__((ext_vector_type(8))) __bf16 bf16x8;
typedef __attribute__((ext_vector_type(4))) __bf16 bf16x4;
typedef __attribute__((ext_vector_type(4))) float f32x4;
typedef __attribute__((ext_vector_type(4))) unsigned int uint4v;

#define QSCALE 0.1803368801111204f  /* 0.125 * log2(e) */

// async global->LDS, 16B per lane; LDS dst = wave-uniform base + lane*16
static __device__ inline void glds16(const bf16_t* g, bf16_t* l) {
    __builtin_amdgcn_global_load_lds(
        (__attribute__((address_space(1))) const void*)g,
        (__attribute__((address_space(3))) void*)l,
        16, 0, 0);
}

// raw hardware v_exp_f32 (input bounded — no libm range/denorm fixup needed)
static __device__ inline float hwexp2(float x) {
#if __has_builtin(__builtin_amdgcn_exp2f)
    return __builtin_amdgcn_exp2f(x);
#else
    float r;
    asm("v_exp_f32 %0, %1" : "=v"(r) : "v"(x));
    return r;
#endif
}

// pack two fp32 -> bf16x2 by truncation (top 16 bits), single v_perm_b32
static __device__ inline unsigned int pack_trunc(float lo, float hi) {
    return __builtin_amdgcn_perm(__builtin_bit_cast(unsigned int, hi),
                                 __builtin_bit_cast(unsigned int, lo),
                                 0x07060302u);
}

// ---------------------------------------------------------------------------
// Fused prep: patch-embed GEMM (by < 64) + qkv_w fp32->bf16 cvt (by >= 64).
// ---------------------------------------------------------------------------
__global__ __launch_bounds__(256) void prep_kernel(const float* __restrict__ x,
                                                   const float* __restrict__ pw,
                                                   const float* __restrict__ pb,
                                                   float* __restrict__ tok,
                                                   const float* __restrict__ qkv_w,
                                                   bf16_t* __restrict__ qw_b) {
    const int tid = threadIdx.x;

    if (blockIdx.y >= 64) {
        // ---- cvt slice: (by-64)*12 + bx in [0, 1728) ----
        int id = (blockIdx.y - 64) * 12 + blockIdx.x;
        int i = id * 256 + tid;                    // < 442368 always (exact)
        float4 v = ((const float4*)qkv_w)[i];
        bf16x4 o = {(bf16_t)v.x, (bf16_t)v.y, (bf16_t)v.z, (bf16_t)v.w};
        ((bf16x4*)qw_b)[i] = o;
        return;
    }

    const int bn = blockIdx.x;   // 12 embed tiles
    const int bm = blockIdx.y;   // 64 token tiles

    __shared__ bf16_t At[64][264];
    __shared__ bf16_t Bt[64][264];

    #pragma unroll
    for (int t = 0; t < 16; t++) {
        int linear = tid + t * 256;
        int ml = linear >> 6;
        int kv = (linear & 63) << 2;
        int n = bm * 64 + ml;
        int pr = n >> 6, pc = n & 63;
        int i = kv >> 4, j = kv & 15;
        float4 v = *(const float4*)(x + (pr * 16 + i) * 1024 + pc * 16 + j);
        bf16x4 o = {(bf16_t)v.x, (bf16_t)v.y, (bf16_t)v.z, (bf16_t)v.w};
        *(bf16x4*)(&At[ml][kv]) = o;
    }
    #pragma unroll
    for (int t = 0; t < 8; t++) {
        int linear = tid + t * 256;
        int nl = linear >> 5;
        int kv = (linear & 31) << 3;
        const float* src = pw + (size_t)(bn * 64 + nl) * 256 + kv;
        float4 v0 = *(const float4*)(src);
        float4 v1 = *(const float4*)(src + 4);
        bf16x8 o = {(bf16_t)v0.x, (bf16_t)v0.y, (bf16_t)v0.z, (bf16_t)v0.w,
                    (bf16_t)v1.x, (bf16_t)v1.y, (bf16_t)v1.z, (bf16_t)v1.w};
        *(bf16x8*)(&Bt[nl][kv]) = o;
    }
    __syncthreads();

    const int lane = tid & 63, wid = tid >> 6, ln = lane & 15, quad = lane >> 4;
    f32x4 acc[4];
    #pragma unroll
    for (int s = 0; s < 4; s++) acc[s] = {0.f, 0.f, 0.f, 0.f};

    #pragma unroll
    for (int kk = 0; kk < 8; kk++) {
        bf16x8 af = *(const bf16x8*)(&At[wid * 16 + ln][kk * 32 + quad * 8]);
        #pragma unroll
        for (int s = 0; s < 4; s++) {
            bf16x8 bfr = *(const bf16x8*)(&Bt[s * 16 + ln][kk * 32 + quad * 8]);
            acc[s] = __builtin_amdgcn_mfma_f32_16x16x32_bf16(af, bfr, acc[s], 0, 0, 0);
        }
    }

    #pragma unroll
    for (int s = 0; s < 4; s++) {
        int e = bn * 64 + s * 16 + ln;
        float bias = pb[e];
        #pragma unroll
        for (int r = 0; r < 4; r++) {
            int m = bm * 64 + wid * 16 + quad * 4 + r;
            tok[(size_t)m * 768 + e] = acc[s][r] + bias;
        }
    }
}

// ---------------------------------------------------------------------------
// LayerNorm per token (768), fp32 stats, bf16 out.
// ---------------------------------------------------------------------------
__global__ __launch_bounds__(256) void ln_kernel(const float* __restrict__ tok,
                                                 const float* __restrict__ g,
                                                 const float* __restrict__ b,
                                                 bf16_t* __restrict__ out) {
    const int n = blockIdx.x;
    const int tid = threadIdx.x;
    const float* row = tok + (size_t)n * 768;
    float x0 = row[tid], x1 = row[tid + 256], x2 = row[tid + 512];
    float s = x0 + x1 + x2;
    float s2 = x0 * x0 + x1 * x1 + x2 * x2;
    #pragma unroll
    for (int off = 32; off; off >>= 1) {
        s += __shfl_xor(s, off);
        s2 += __shfl_xor(s2, off);
    }
    __shared__ float ws1[4], ws2[4];
    int wid = tid >> 6;
    if ((tid & 63) == 0) { ws1[wid] = s; ws2[wid] = s2; }
    __syncthreads();
    s = ws1[0] + ws1[1] + ws1[2] + ws1[3];
    s2 = ws2[0] + ws2[1] + ws2[2] + ws2[3];
    float mu = s * (1.f / 768.f);
    float var = s2 * (1.f / 768.f) - mu * mu;
    float r = rsqrtf(var + 1e-6f);
    bf16_t* orow = out + (size_t)n * 768;
    orow[tid]       = (bf16_t)((x0 - mu) * r * g[tid]       + b[tid]);
    orow[tid + 256] = (bf16_t)((x1 - mu) * r * g[tid + 256] + b[tid + 256]);
    orow[tid + 512] = (bf16_t)((x2 - mu) * r * g[tid + 512] + b[tid + 512]);
}

// ---------------------------------------------------------------------------
// QKV GEMM: bn-fastest grid (36, 32), 128(M)x64(N) tile, BK=64, async dbuf
// glds16 staging with XOR-swizzled LDS. bn: 0..11 = q, 12..23 = k, 24..35 = v.
// ---------------------------------------------------------------------------
__global__ __launch_bounds__(256) void qkv_gemm(const bf16_t* __restrict__ tokb,
                                                const bf16_t* __restrict__ wq,
                                                bf16_t* __restrict__ qb,
                                                bf16_t* __restrict__ kswz,
                                                bf16_t* __restrict__ vswz) {
    const int bn = blockIdx.x;   // 36 n-tiles (64 cols = one head of q/k/v)
    const int bm = blockIdx.y;   // 32 m-tiles (128 tokens)
    const int tid = threadIdx.x;
    const int wid = tid >> 6, lane = tid & 63;
    const int ln = lane & 15, quad = lane >> 4;
    const int wm = wid & 1, wn = wid >> 1;

    __shared__ bf16_t Asw[2][8192];   // 128 rows x 8 chunks x 8 bf16
    __shared__ bf16_t Bsw[2][4096];   // 64 rows x 8 chunks

    f32x4 acc[4][2];
    #pragma unroll
    for (int sm = 0; sm < 4; sm++)
        #pragma unroll
        for (int sn = 0; sn < 2; sn++) acc[sm][sn] = {0.f, 0.f, 0.f, 0.f};

    // staging: per wave, A chunks [wid*256, +256) (4 issues), B [wid*128, +128) (2)
    auto stage = [&](int kb0, int buf) {
        #pragma unroll
        for (int i = 0; i < 4; i++) {
            int L = wid * 256 + i * 64 + lane;
            int r = L >> 3, c = L & 7;
            int gc = c ^ (r & 7);
            glds16(tokb + (size_t)(bm * 128 + r) * 768 + kb0 + gc * 8,
                   Asw[buf] + (wid * 256 + i * 64) * 8);
        }
        #pragma unroll
        for (int i = 0; i < 2; i++) {
            int L = wid * 128 + i * 64 + lane;
            int r = L >> 3, c = L & 7;
            int gc = c ^ (r & 7);
            glds16(wq + (size_t)(bn * 64 + r) * 768 + kb0 + gc * 8,
                   Bsw[buf] + (wid * 128 + i * 64) * 8);
        }
    };

    auto compute = [&](const bf16_t* Ab, const bf16_t* Bb) {
        #pragma unroll
        for (int kk = 0; kk < 2; kk++) {
            const int c = (kk * 4 + quad) ^ (ln & 7);
            bf16x8 af[4], bfr[2];
            #pragma unroll
            for (int sm = 0; sm < 4; sm++) {
                int row = wm * 64 + sm * 16 + ln;
                af[sm] = *(const bf16x8*)(Ab + (row * 8 + c) * 8);
            }
            #pragma unroll
            for (int sn = 0; sn < 2; sn++) {
                int row = wn * 32 + sn * 16 + ln;
                bfr[sn] = *(const bf16x8*)(Bb + (row * 8 + c) * 8);
            }
            #pragma unroll
            for (int sm = 0; sm < 4; sm++)
                #pragma unroll
                for (int sn = 0; sn < 2; sn++)
                    acc[sm][sn] = __builtin_amdgcn_mfma_f32_16x16x32_bf16(af[sm], bfr[sn], acc[sm][sn], 0, 0, 0);
        }
    };

    stage(0, 0);

    for (int s = 0; s < 12; s += 2) {
        __builtin_amdgcn_s_barrier();                 // prev reads of buf1 done
        stage((s + 1) * 64, 1);
        __builtin_amdgcn_s_waitcnt(0x0F76);           // vmcnt(6): buf0 resident
        __builtin_amdgcn_s_barrier();
        compute(Asw[0], Bsw[0]);
        __builtin_amdgcn_s_barrier();                 // prev reads of buf0 done
        if (s + 2 < 12) {
            stage((s + 2) * 64, 0);
            __builtin_amdgcn_s_waitcnt(0x0F76);       // vmcnt(6)
        } else {
            __builtin_amdgcn_s_waitcnt(0x0F70);       // vmcnt(0)
        }
        __builtin_amdgcn_s_barrier();
        compute(Asw[1], Bsw[1]);
    }

    const int sidx = bn / 12;                  // 0=q 1=k 2=v (block-uniform)
    const int head = bn % 12;
    #pragma unroll
    for (int sn = 0; sn < 2; sn++) {
        int dc = wn * 32 + sn * 16 + ln;       // 0..63 within head
        #pragma unroll
        for (int sm = 0; sm < 4; sm++) {
            #pragma unroll
            for (int r = 0; r < 4; r++) {
                int m = bm * 128 + wm * 64 + sm * 16 + quad * 4 + r;   // token = key
                float v = acc[sm][sn][r];
                if (sidx == 0) {
                    qb[((size_t)(head * 4096 + m)) * 64 + dc] = (bf16_t)(v * QSCALE);
                } else if (sidx == 1) {
                    bf16_t val = (bf16_t)v;
                    int kt = m >> 6, sb = (m >> 4) & 3, lnk = m & 15;
                    int half = dc >> 5, quadk = (dc >> 3) & 3, j = dc & 7;
                    int l = quadk * 16 + lnk;
                    kswz[((size_t)(head * 64 + kt)) * 4096 + sb * 1024 + half * 512 + l * 8 + j] = val;
                } else {
                    bf16_t val = (bf16_t)v;
                    int kt = m >> 6, keyl = m & 63;
                    int sblk = keyl >> 4;
                    int mm = sblk >> 1, tb = sblk & 1;
                    int w16 = keyl & 15, qv = w16 >> 2, jj = w16 & 3;
                    int jp = tb * 4 + jj;
                    int db = dc >> 4, lnv = dc & 15;
                    int l = qv * 16 + lnv;
                    vswz[((size_t)(head * 64 + kt)) * 4096 + ((mm * 4 + db) * 64 + l) * 8 + jp] = val;
                }
            }
        }
    }
}

// ---------------------------------------------------------------------------
// Attention v11 = v10 + T5 s_setprio around the MFMA/exp compute cluster.
// v10 landed at 60.9us = ~sum of pipe demands (MFMA 28 + LDS 30 + VALU 13,
// poorly overlapped). With 3 de-phased blocks/CU, setprio(1) biases the CU
// scheduler toward the wave currently in its MFMA cluster (m191: +4-7% attn
// in exactly this regime; null only for lockstep single-block GEMM).
// Tripwires: VGPR <= 64 (occupancy step), WRITE_SIZE ~12.3MB.
// If attn is unchanged (+-1us), T5 is null here and this attn structure is
// at its limit.
// ---------------------------------------------------------------------------
__global__ __launch_bounds__(256, 4) void attn_full(const bf16_t* __restrict__ qbuf,
                                                    const bf16_t* __restrict__ kswz,
                                                    const bf16_t* __restrict__ vswz,
                                                    float* __restrict__ out) {
    const int h = blockIdx.y;
    const int tid = threadIdx.x;
    const int wid = tid >> 6;           // 0..3
    const int lane = tid & 63;
    const int ln = lane & 15, quad = lane >> 4;
    const int qh = wid & 1;             // which 32-query half of the 64q block
    const int kh = wid >> 1;            // which 2048-key half (block split-K)
    const int q0 = blockIdx.x * 64;

    // staging: K [2 kh][2 buf][2048] at 0, V same at +16384 (32KB total);
    // combine view after syncthreads: [64][68] f32 + l[64] = 17.7KB (fits).
    __shared__ __align__(16) char RAW[32768];
    bf16_t* Kst = (bf16_t*)RAW;
    bf16_t* Vst = (bf16_t*)(RAW + 16384);

    // Q B-frags for this wave's two 16-query groups (32 queries/wave)
    bf16x8 qf[2][2];
    #pragma unroll
    for (int g = 0; g < 2; g++) {
        const int q0g = q0 + qh * 32 + g * 16;
        const bf16_t* qrow = qbuf + ((size_t)h * 4096 + q0g + ln) * 64;
        qf[g][0] = *(const bf16x8*)(qrow + quad * 8);
        qf[g][1] = *(const bf16x8*)(qrow + 32 + quad * 8);
    }

    // all-ones A fragment for the l row-sum MFMA
    bf16x8 ones;
    #pragma unroll
    for (int i = 0; i < 8; i++) ones[i] = (bf16_t)1.0f;

    // this pair's 32-tile (= 64 half-tile) key sub-range
    const bf16_t* kg = kswz + (size_t)h * 64 * 4096 + (size_t)(kh * 32) * 4096;
    const bf16_t* vg = vswz + (size_t)h * 64 * 4096 + (size_t)(kh * 32) * 4096;

    f32x4 accO[2][4];
    f32x4 accL[2];
    #pragma unroll
    for (int g = 0; g < 2; g++) {
        accL[g] = {0.f, 0.f, 0.f, 0.f};
        #pragma unroll
        for (int d = 0; d < 4; d++) accO[g][d] = {0.f, 0.f, 0.f, 0.f};
    }

    // stage one 4KB K + 4KB V half-tile (32 keys) per kh pair; the pair's
    // two waves (qh) each cover half: 2 K + 2 V glds16 per wave
    auto stage = [&](int ht, int buf) {
        const bf16_t* kt_g = kg + (size_t)ht * 2048;
        const bf16_t* vt_g = vg + (size_t)ht * 2048;
        bf16_t* kl = Kst + (kh * 2 + buf) * 2048 + qh * 1024;
        bf16_t* vl = Vst + (kh * 2 + buf) * 2048 + qh * 1024;
        #pragma unroll
        for (int i = 0; i < 2; i++) {
            glds16(kt_g + qh * 1024 + i * 512 + lane * 8, kl + i * 512);
            glds16(vt_g + qh * 1024 + i * 512 + lane * 8, vl + i * 512);
        }
    };

    // one 32-key half-tile; minimal-liveness sequencing: each S-tile's exp
    // + pack is consumed before the next S-tile is produced.
    auto compute = [&](const bf16_t* Kb, const bf16_t* Vb) {
        bf16x8 vf0 = *(const bf16x8*)(Vb + 0 * 512 + lane * 8);
        bf16x8 vf1 = *(const bf16x8*)(Vb + 1 * 512 + lane * 8);
        bf16x8 vf2 = *(const bf16x8*)(Vb + 2 * 512 + lane * 8);
        bf16x8 vf3 = *(const bf16x8*)(Vb + 3 * 512 + lane * 8);
        bf16x8 ka0 = *(const bf16x8*)(Kb + lane * 8);
        bf16x8 ka1 = *(const bf16x8*)(Kb + 512 + lane * 8);
        bf16x8 kb0 = *(const bf16x8*)(Kb + 1024 + lane * 8);
        bf16x8 kb1 = *(const bf16x8*)(Kb + 1536 + lane * 8);
        __builtin_amdgcn_s_setprio(1);
        #pragma unroll
        for (int g = 0; g < 2; g++) {
            f32x4 z = {0.f, 0.f, 0.f, 0.f};
            f32x4 SA = __builtin_amdgcn_mfma_f32_16x16x32_bf16(ka0, qf[g][0], z, 0, 0, 0);
            SA = __builtin_amdgcn_mfma_f32_16x16x32_bf16(ka1, qf[g][1], SA, 0, 0, 0);
            unsigned int u0 = pack_trunc(hwexp2(SA[0]), hwexp2(SA[1]));
            unsigned int u1 = pack_trunc(hwexp2(SA[2]), hwexp2(SA[3]));
            f32x4 SB = __builtin_amdgcn_mfma_f32_16x16x32_bf16(kb0, qf[g][0], z, 0, 0, 0);
            SB = __builtin_amdgcn_mfma_f32_16x16x32_bf16(kb1, qf[g][1], SB, 0, 0, 0);
            unsigned int u2 = pack_trunc(hwexp2(SB[0]), hwexp2(SB[1]));
            unsigned int u3 = pack_trunc(hwexp2(SB[2]), hwexp2(SB[3]));
            uint4v u = {u0, u1, u2, u3};
            bf16x8 pb = __builtin_bit_cast(bf16x8, u);
            accL[g] = __builtin_amdgcn_mfma_f32_16x16x32_bf16(ones, pb, accL[g], 0, 0, 0);
            accO[g][0] = __builtin_amdgcn_mfma_f32_16x16x32_bf16(vf0, pb, accO[g][0], 0, 0, 0);
            accO[g][1] = __builtin_amdgcn_mfma_f32_16x16x32_bf16(vf1, pb, accO[g][1], 0, 0, 0);
            accO[g][2] = __builtin_amdgcn_mfma_f32_16x16x32_bf16(vf2, pb, accO[g][2], 0, 0, 0);
            accO[g][3] = __builtin_amdgcn_mfma_f32_16x16x32_bf16(vf3, pb, accO[g][3], 0, 0, 0);
        }
        __builtin_amdgcn_s_setprio(0);
    };

    stage(0, 0);

    const bf16_t* K0 = Kst + (kh * 2 + 0) * 2048;
    const bf16_t* V0 = Vst + (kh * 2 + 0) * 2048;
    const bf16_t* K1 = Kst + (kh * 2 + 1) * 2048;
    const bf16_t* V1 = Vst + (kh * 2 + 1) * 2048;

    for (int ht = 0; ht < 64; ht += 2) {
        __builtin_amdgcn_s_barrier();                 // prev reads of buf1 done
        stage(ht + 1, 1);
        __builtin_amdgcn_s_waitcnt(0x0F74);           // vmcnt(4): half-tile ht resident
        __builtin_amdgcn_s_barrier();
        compute(K0, V0);
        __builtin_amdgcn_s_barrier();                 // prev reads of buf0 done
        if (ht + 2 < 64) {
            stage(ht + 2, 0);
            __builtin_amdgcn_s_waitcnt(0x0F74);       // vmcnt(4)
        } else {
            __builtin_amdgcn_s_waitcnt(0x0F70);       // vmcnt(0)
        }
        __builtin_amdgcn_s_barrier();
        compute(K1, V1);
    }

    // ---- block-internal split-K combine + inline normalize ----
    __syncthreads();   // all K/V reads done; RAW reusable
    float* comb  = (float*)RAW;               // [64][68] f32, 17408 B
    float* combl = (float*)(RAW + 17408);     // 64 f32
    if (kh == 1) {
        #pragma unroll
        for (int g = 0; g < 2; g++) {
            const int lq = qh * 32 + g * 16 + ln;
            #pragma unroll
            for (int db = 0; db < 4; db++)
                *(f32x4*)&comb[lq * 68 + db * 16 + quad * 4] = accO[g][db];
            if (quad == 0) combl[lq] = accL[g][0];
        }
    }
    __syncthreads();
    if (kh == 0) {
        #pragma unroll
        for (int g = 0; g < 2; g++) {
            const int lq = qh * 32 + g * 16 + ln;
            const int qg = q0 + lq;
            // every lane's accL[g][0] holds l[q=ln] (rows identical for ones-A)
            float inv = 1.0f / (accL[g][0] + combl[lq]);
            float* op = out + (size_t)qg * 768 + h * 64 + quad * 4;
            #pragma unroll
            for (int db = 0; db < 4; db++) {
                f32x4 o = (accO[g][db] + *(const f32x4*)&comb[lq * 68 + db * 16 + quad * 4]);
                o *= inv;
                *(f32x4*)(op + db * 16) = o;
            }
        }
    }
}

// ---------------------------------------------------------------------------
extern "C" void kernel_launch(void* const* d_in, const int* in_sizes, int n_in,
                              void* d_out, int out_size, void* d_ws, size_t ws_size,
                              hipStream_t stream) {
    const float* x      = (const float*)d_in[0];
    const float* proj_w = (const float*)d_in[1];
    const float* proj_b = (const float*)d_in[2];
    const float* ln_g   = (const float*)d_in[3];
    const float* ln_b   = (const float*)d_in[4];
    const float* qkv_w  = (const float*)d_in[5];
    float* out = (float*)d_out;

    char* ws = (char*)d_ws;
    float*  tok_pre = (float*)(ws + 0);              // 12,582,912 B
    bf16_t* tok_b   = (bf16_t*)(ws + 12582912);      //  6,291,456 B
    bf16_t* qw_b    = (bf16_t*)(ws + 18874368);      //  3,538,944 B
    bf16_t* qbuf    = (bf16_t*)(ws + 22413312);      //  6,291,456 B
    bf16_t* kswz    = (bf16_t*)(ws + 28704768);      //  6,291,456 B
    bf16_t* vswz    = (bf16_t*)(ws + 34996224);      //  6,291,456 B (total ~41.3 MB)

    // patch tiles (by<64) + qkv_w cvt (by in [64,208))
    prep_kernel<<<dim3(12, 208), 256, 0, stream>>>(x, proj_w, proj_b, tok_pre, qkv_w, qw_b);
    ln_kernel<<<4096, 256, 0, stream>>>(tok_pre, ln_g, ln_b, tok_b);
    qkv_gemm<<<dim3(36, 32), 256, 0, stream>>>(tok_b, qw_b, qbuf, kswz, vswz);
    attn_full<<<dim3(64, 12), 256, 0, stream>>>(qbuf, kswz, vswz, out);
}

// Round 11
// 165.088 us; speedup vs baseline: 1.0669x; 1.0669x over previous
//
#include <hip/hip_runtime.h>
#include <hip/hip_bf16.h>

typedef __bf16 bf16_t;
typedef __attribute__((ext_vector_type(8))) __bf16 bf16x8;
typedef __attribute__((ext_vector_type(4))) __bf16 bf16x4;
typedef __attribute__((ext_vector_type(4))) float f32x4;
typedef __attribute__((ext_vector_type(4))) unsigned int uint4v;

#define QSCALE 0.1803368801111204f  /* 0.125 * log2(e) */

// async global->LDS, 16B per lane; LDS dst = wave-uniform base + lane*16
static __device__ inline void glds16(const bf16_t* g, bf16_t* l) {
    __builtin_amdgcn_global_load_lds(
        (__attribute__((address_space(1))) const void*)g,
        (__attribute__((address_space(3))) void*)l,
        16, 0, 0);
}

// raw hardware v_exp_f32 (input bounded — no libm range/denorm fixup needed)
static __device__ inline float hwexp2(float x) {
#if __has_builtin(__builtin_amdgcn_exp2f)
    return __builtin_amdgcn_exp2f(x);
#else
    float r;
    asm("v_exp_f32 %0, %1" : "=v"(r) : "v"(x));
    return r;
#endif
}

// pack two fp32 -> bf16x2 by truncation (top 16 bits), single v_perm_b32
static __device__ inline unsigned int pack_trunc(float lo, float hi) {
    return __builtin_amdgcn_perm(__builtin_bit_cast(unsigned int, hi),
                                 __builtin_bit_cast(unsigned int, lo),
                                 0x07060302u);
}

// ---------------------------------------------------------------------------
// Fused prep: patch-embed GEMM (by < 64) + qkv_w fp32->bf16 cvt (by >= 64).
// ---------------------------------------------------------------------------
__global__ __launch_bounds__(256) void prep_kernel(const float* __restrict__ x,
                                                   const float* __restrict__ pw,
                                                   const float* __restrict__ pb,
                                                   float* __restrict__ tok,
                                                   const float* __restrict__ qkv_w,
                                                   bf16_t* __restrict__ qw_b) {
    const int tid = threadIdx.x;

    if (blockIdx.y >= 64) {
        // ---- cvt slice: (by-64)*12 + bx in [0, 1728) ----
        int id = (blockIdx.y - 64) * 12 + blockIdx.x;
        int i = id * 256 + tid;                    // < 442368 always (exact)
        float4 v = ((const float4*)qkv_w)[i];
        bf16x4 o = {(bf16_t)v.x, (bf16_t)v.y, (bf16_t)v.z, (bf16_t)v.w};
        ((bf16x4*)qw_b)[i] = o;
        return;
    }

    const int bn = blockIdx.x;   // 12 embed tiles
    const int bm = blockIdx.y;   // 64 token tiles

    __shared__ bf16_t At[64][264];
    __shared__ bf16_t Bt[64][264];

    #pragma unroll
    for (int t = 0; t < 16; t++) {
        int linear = tid + t * 256;
        int ml = linear >> 6;
        int kv = (linear & 63) << 2;
        int n = bm * 64 + ml;
        int pr = n >> 6, pc = n & 63;
        int i = kv >> 4, j = kv & 15;
        float4 v = *(const float4*)(x + (pr * 16 + i) * 1024 + pc * 16 + j);
        bf16x4 o = {(bf16_t)v.x, (bf16_t)v.y, (bf16_t)v.z, (bf16_t)v.w};
        *(bf16x4*)(&At[ml][kv]) = o;
    }
    #pragma unroll
    for (int t = 0; t < 8; t++) {
        int linear = tid + t * 256;
        int nl = linear >> 5;
        int kv = (linear & 31) << 3;
        const float* src = pw + (size_t)(bn * 64 + nl) * 256 + kv;
        float4 v0 = *(const float4*)(src);
        float4 v1 = *(const float4*)(src + 4);
        bf16x8 o = {(bf16_t)v0.x, (bf16_t)v0.y, (bf16_t)v0.z, (bf16_t)v0.w,
                    (bf16_t)v1.x, (bf16_t)v1.y, (bf16_t)v1.z, (bf16_t)v1.w};
        *(bf16x8*)(&Bt[nl][kv]) = o;
    }
    __syncthreads();

    const int lane = tid & 63, wid = tid >> 6, ln = lane & 15, quad = lane >> 4;
    f32x4 acc[4];
    #pragma unroll
    for (int s = 0; s < 4; s++) acc[s] = {0.f, 0.f, 0.f, 0.f};

    #pragma unroll
    for (int kk = 0; kk < 8; kk++) {
        bf16x8 af = *(const bf16x8*)(&At[wid * 16 + ln][kk * 32 + quad * 8]);
        #pragma unroll
        for (int s = 0; s < 4; s++) {
            bf16x8 bfr = *(const bf16x8*)(&Bt[s * 16 + ln][kk * 32 + quad * 8]);
            acc[s] = __builtin_amdgcn_mfma_f32_16x16x32_bf16(af, bfr, acc[s], 0, 0, 0);
        }
    }

    #pragma unroll
    for (int s = 0; s < 4; s++) {
        int e = bn * 64 + s * 16 + ln;
        float bias = pb[e];
        #pragma unroll
        for (int r = 0; r < 4; r++) {
            int m = bm * 64 + wid * 16 + quad * 4 + r;
            tok[(size_t)m * 768 + e] = acc[s][r] + bias;
        }
    }
}

// ---------------------------------------------------------------------------
// LayerNorm per token (768), fp32 stats, bf16 out.
// ---------------------------------------------------------------------------
__global__ __launch_bounds__(256) void ln_kernel(const float* __restrict__ tok,
                                                 const float* __restrict__ g,
                                                 const float* __restrict__ b,
                                                 bf16_t* __restrict__ out) {
    const int n = blockIdx.x;
    const int tid = threadIdx.x;
    const float* row = tok + (size_t)n * 768;
    float x0 = row[tid], x1 = row[tid + 256], x2 = row[tid + 512];
    float s = x0 + x1 + x2;
    float s2 = x0 * x0 + x1 * x1 + x2 * x2;
    #pragma unroll
    for (int off = 32; off; off >>= 1) {
        s += __shfl_xor(s, off);
        s2 += __shfl_xor(s2, off);
    }
    __shared__ float ws1[4], ws2[4];
    int wid = tid >> 6;
    if ((tid & 63) == 0) { ws1[wid] = s; ws2[wid] = s2; }
    __syncthreads();
    s = ws1[0] + ws1[1] + ws1[2] + ws1[3];
    s2 = ws2[0] + ws2[1] + ws2[2] + ws2[3];
    float mu = s * (1.f / 768.f);
    float var = s2 * (1.f / 768.f) - mu * mu;
    float r = rsqrtf(var + 1e-6f);
    bf16_t* orow = out + (size_t)n * 768;
    orow[tid]       = (bf16_t)((x0 - mu) * r * g[tid]       + b[tid]);
    orow[tid + 256] = (bf16_t)((x1 - mu) * r * g[tid + 256] + b[tid + 256]);
    orow[tid + 512] = (bf16_t)((x2 - mu) * r * g[tid + 512] + b[tid + 512]);
}

// ---------------------------------------------------------------------------
// QKV GEMM: bn-fastest grid (36, 32), 128(M)x64(N) tile, BK=64, async dbuf
// glds16 staging with XOR-swizzled LDS. bn: 0..11 = q, 12..23 = k, 24..35 = v.
// v12: __launch_bounds__(256,4) — same occupancy step as attn v9: acc is 32
// AGPR (<=64 granule), transient VGPR squeezed to <=64 -> 128 regs/wave ->
// 4 waves/SIMD (12 waves/CU with 48KB LDS / 3 blocks) instead of 2/SIMD.
// ---------------------------------------------------------------------------
__global__ __launch_bounds__(256, 4) void qkv_gemm(const bf16_t* __restrict__ tokb,
                                                   const bf16_t* __restrict__ wq,
                                                   bf16_t* __restrict__ qb,
                                                   bf16_t* __restrict__ kswz,
                                                   bf16_t* __restrict__ vswz) {
    const int bn = blockIdx.x;   // 36 n-tiles (64 cols = one head of q/k/v)
    const int bm = blockIdx.y;   // 32 m-tiles (128 tokens)
    const int tid = threadIdx.x;
    const int wid = tid >> 6, lane = tid & 63;
    const int ln = lane & 15, quad = lane >> 4;
    const int wm = wid & 1, wn = wid >> 1;

    __shared__ bf16_t Asw[2][8192];   // 128 rows x 8 chunks x 8 bf16
    __shared__ bf16_t Bsw[2][4096];   // 64 rows x 8 chunks

    f32x4 acc[4][2];
    #pragma unroll
    for (int sm = 0; sm < 4; sm++)
        #pragma unroll
        for (int sn = 0; sn < 2; sn++) acc[sm][sn] = {0.f, 0.f, 0.f, 0.f};

    // staging: per wave, A chunks [wid*256, +256) (4 issues), B [wid*128, +128) (2)
    auto stage = [&](int kb0, int buf) {
        #pragma unroll
        for (int i = 0; i < 4; i++) {
            int L = wid * 256 + i * 64 + lane;
            int r = L >> 3, c = L & 7;
            int gc = c ^ (r & 7);
            glds16(tokb + (size_t)(bm * 128 + r) * 768 + kb0 + gc * 8,
                   Asw[buf] + (wid * 256 + i * 64) * 8);
        }
        #pragma unroll
        for (int i = 0; i < 2; i++) {
            int L = wid * 128 + i * 64 + lane;
            int r = L >> 3, c = L & 7;
            int gc = c ^ (r & 7);
            glds16(wq + (size_t)(bn * 64 + r) * 768 + kb0 + gc * 8,
                   Bsw[buf] + (wid * 128 + i * 64) * 8);
        }
    };

    auto compute = [&](const bf16_t* Ab, const bf16_t* Bb) {
        #pragma unroll
        for (int kk = 0; kk < 2; kk++) {
            const int c = (kk * 4 + quad) ^ (ln & 7);
            bf16x8 af[4], bfr[2];
            #pragma unroll
            for (int sm = 0; sm < 4; sm++) {
                int row = wm * 64 + sm * 16 + ln;
                af[sm] = *(const bf16x8*)(Ab + (row * 8 + c) * 8);
            }
            #pragma unroll
            for (int sn = 0; sn < 2; sn++) {
                int row = wn * 32 + sn * 16 + ln;
                bfr[sn] = *(const bf16x8*)(Bb + (row * 8 + c) * 8);
            }
            #pragma unroll
            for (int sm = 0; sm < 4; sm++)
                #pragma unroll
                for (int sn = 0; sn < 2; sn++)
                    acc[sm][sn] = __builtin_amdgcn_mfma_f32_16x16x32_bf16(af[sm], bfr[sn], acc[sm][sn], 0, 0, 0);
        }
    };

    stage(0, 0);

    for (int s = 0; s < 12; s += 2) {
        __builtin_amdgcn_s_barrier();                 // prev reads of buf1 done
        stage((s + 1) * 64, 1);
        __builtin_amdgcn_s_waitcnt(0x0F76);           // vmcnt(6): buf0 resident
        __builtin_amdgcn_s_barrier();
        compute(Asw[0], Bsw[0]);
        __builtin_amdgcn_s_barrier();                 // prev reads of buf0 done
        if (s + 2 < 12) {
            stage((s + 2) * 64, 0);
            __builtin_amdgcn_s_waitcnt(0x0F76);       // vmcnt(6)
        } else {
            __builtin_amdgcn_s_waitcnt(0x0F70);       // vmcnt(0)
        }
        __builtin_amdgcn_s_barrier();
        compute(Asw[1], Bsw[1]);
    }

    const int sidx = bn / 12;                  // 0=q 1=k 2=v (block-uniform)
    const int head = bn % 12;
    #pragma unroll
    for (int sn = 0; sn < 2; sn++) {
        int dc = wn * 32 + sn * 16 + ln;       // 0..63 within head
        #pragma unroll
        for (int sm = 0; sm < 4; sm++) {
            #pragma unroll
            for (int r = 0; r < 4; r++) {
                int m = bm * 128 + wm * 64 + sm * 16 + quad * 4 + r;   // token = key
                float v = acc[sm][sn][r];
                if (sidx == 0) {
                    qb[((size_t)(head * 4096 + m)) * 64 + dc] = (bf16_t)(v * QSCALE);
                } else if (sidx == 1) {
                    bf16_t val = (bf16_t)v;
                    int kt = m >> 6, sb = (m >> 4) & 3, lnk = m & 15;
                    int half = dc >> 5, quadk = (dc >> 3) & 3, j = dc & 7;
                    int l = quadk * 16 + lnk;
                    kswz[((size_t)(head * 64 + kt)) * 4096 + sb * 1024 + half * 512 + l * 8 + j] = val;
                } else {
                    bf16_t val = (bf16_t)v;
                    int kt = m >> 6, keyl = m & 63;
                    int sblk = keyl >> 4;
                    int mm = sblk >> 1, tb = sblk & 1;
                    int w16 = keyl & 15, qv = w16 >> 2, jj = w16 & 3;
                    int jp = tb * 4 + jj;
                    int db = dc >> 4, lnv = dc & 15;
                    int l = qv * 16 + lnv;
                    vswz[((size_t)(head * 64 + kt)) * 4096 + ((mm * 4 + db) * 64 + l) * 8 + jp] = val;
                }
            }
        }
    }
}

// ---------------------------------------------------------------------------
// Attention v12 = v10 exactly (setprio removed: T5 measured -4us here —
// with 2 barrier-locked waves/SIMD it deprioritized co-resident blocks'
// staging waves). 32q/wave, 64V/40A regs (4-wave/SIMD step), half-tile
// glds dbuf, kh split-K pair, inline normalize.
// ---------------------------------------------------------------------------
__global__ __launch_bounds__(256, 4) void attn_full(const bf16_t* __restrict__ qbuf,
                                                    const bf16_t* __restrict__ kswz,
                                                    const bf16_t* __restrict__ vswz,
                                                    float* __restrict__ out) {
    const int h = blockIdx.y;
    const int tid = threadIdx.x;
    const int wid = tid >> 6;           // 0..3
    const int lane = tid & 63;
    const int ln = lane & 15, quad = lane >> 4;
    const int qh = wid & 1;             // which 32-query half of the 64q block
    const int kh = wid >> 1;            // which 2048-key half (block split-K)
    const int q0 = blockIdx.x * 64;

    // staging: K [2 kh][2 buf][2048] at 0, V same at +16384 (32KB total);
    // combine view after syncthreads: [64][68] f32 + l[64] = 17.7KB (fits).
    __shared__ __align__(16) char RAW[32768];
    bf16_t* Kst = (bf16_t*)RAW;
    bf16_t* Vst = (bf16_t*)(RAW + 16384);

    // Q B-frags for this wave's two 16-query groups (32 queries/wave)
    bf16x8 qf[2][2];
    #pragma unroll
    for (int g = 0; g < 2; g++) {
        const int q0g = q0 + qh * 32 + g * 16;
        const bf16_t* qrow = qbuf + ((size_t)h * 4096 + q0g + ln) * 64;
        qf[g][0] = *(const bf16x8*)(qrow + quad * 8);
        qf[g][1] = *(const bf16x8*)(qrow + 32 + quad * 8);
    }

    // all-ones A fragment for the l row-sum MFMA
    bf16x8 ones;
    #pragma unroll
    for (int i = 0; i < 8; i++) ones[i] = (bf16_t)1.0f;

    // this pair's 32-tile (= 64 half-tile) key sub-range
    const bf16_t* kg = kswz + (size_t)h * 64 * 4096 + (size_t)(kh * 32) * 4096;
    const bf16_t* vg = vswz + (size_t)h * 64 * 4096 + (size_t)(kh * 32) * 4096;

    f32x4 accO[2][4];
    f32x4 accL[2];
    #pragma unroll
    for (int g = 0; g < 2; g++) {
        accL[g] = {0.f, 0.f, 0.f, 0.f};
        #pragma unroll
        for (int d = 0; d < 4; d++) accO[g][d] = {0.f, 0.f, 0.f, 0.f};
    }

    // stage one 4KB K + 4KB V half-tile (32 keys) per kh pair; the pair's
    // two waves (qh) each cover half: 2 K + 2 V glds16 per wave
    auto stage = [&](int ht, int buf) {
        const bf16_t* kt_g = kg + (size_t)ht * 2048;
        const bf16_t* vt_g = vg + (size_t)ht * 2048;
        bf16_t* kl = Kst + (kh * 2 + buf) * 2048 + qh * 1024;
        bf16_t* vl = Vst + (kh * 2 + buf) * 2048 + qh * 1024;
        #pragma unroll
        for (int i = 0; i < 2; i++) {
            glds16(kt_g + qh * 1024 + i * 512 + lane * 8, kl + i * 512);
            glds16(vt_g + qh * 1024 + i * 512 + lane * 8, vl + i * 512);
        }
    };

    // one 32-key half-tile; minimal-liveness sequencing: each S-tile's exp
    // + pack is consumed before the next S-tile is produced.
    auto compute = [&](const bf16_t* Kb, const bf16_t* Vb) {
        bf16x8 vf0 = *(const bf16x8*)(Vb + 0 * 512 + lane * 8);
        bf16x8 vf1 = *(const bf16x8*)(Vb + 1 * 512 + lane * 8);
        bf16x8 vf2 = *(const bf16x8*)(Vb + 2 * 512 + lane * 8);
        bf16x8 vf3 = *(const bf16x8*)(Vb + 3 * 512 + lane * 8);
        bf16x8 ka0 = *(const bf16x8*)(Kb + lane * 8);
        bf16x8 ka1 = *(const bf16x8*)(Kb + 512 + lane * 8);
        bf16x8 kb0 = *(const bf16x8*)(Kb + 1024 + lane * 8);
        bf16x8 kb1 = *(const bf16x8*)(Kb + 1536 + lane * 8);
        #pragma unroll
        for (int g = 0; g < 2; g++) {
            f32x4 z = {0.f, 0.f, 0.f, 0.f};
            f32x4 SA = __builtin_amdgcn_mfma_f32_16x16x32_bf16(ka0, qf[g][0], z, 0, 0, 0);
            SA = __builtin_amdgcn_mfma_f32_16x16x32_bf16(ka1, qf[g][1], SA, 0, 0, 0);
            unsigned int u0 = pack_trunc(hwexp2(SA[0]), hwexp2(SA[1]));
            unsigned int u1 = pack_trunc(hwexp2(SA[2]), hwexp2(SA[3]));
            f32x4 SB = __builtin_amdgcn_mfma_f32_16x16x32_bf16(kb0, qf[g][0], z, 0, 0, 0);
            SB = __builtin_amdgcn_mfma_f32_16x16x32_bf16(kb1, qf[g][1], SB, 0, 0, 0);
            unsigned int u2 = pack_trunc(hwexp2(SB[0]), hwexp2(SB[1]));
            unsigned int u3 = pack_trunc(hwexp2(SB[2]), hwexp2(SB[3]));
            uint4v u = {u0, u1, u2, u3};
            bf16x8 pb = __builtin_bit_cast(bf16x8, u);
            accL[g] = __builtin_amdgcn_mfma_f32_16x16x32_bf16(ones, pb, accL[g], 0, 0, 0);
            accO[g][0] = __builtin_amdgcn_mfma_f32_16x16x32_bf16(vf0, pb, accO[g][0], 0, 0, 0);
            accO[g][1] = __builtin_amdgcn_mfma_f32_16x16x32_bf16(vf1, pb, accO[g][1], 0, 0, 0);
            accO[g][2] = __builtin_amdgcn_mfma_f32_16x16x32_bf16(vf2, pb, accO[g][2], 0, 0, 0);
            accO[g][3] = __builtin_amdgcn_mfma_f32_16x16x32_bf16(vf3, pb, accO[g][3], 0, 0, 0);
        }
    };

    stage(0, 0);

    const bf16_t* K0 = Kst + (kh * 2 + 0) * 2048;
    const bf16_t* V0 = Vst + (kh * 2 + 0) * 2048;
    const bf16_t* K1 = Kst + (kh * 2 + 1) * 2048;
    const bf16_t* V1 = Vst + (kh * 2 + 1) * 2048;

    for (int ht = 0; ht < 64; ht += 2) {
        __builtin_amdgcn_s_barrier();                 // prev reads of buf1 done
        stage(ht + 1, 1);
        __builtin_amdgcn_s_waitcnt(0x0F74);           // vmcnt(4): half-tile ht resident
        __builtin_amdgcn_s_barrier();
        compute(K0, V0);
        __builtin_amdgcn_s_barrier();                 // prev reads of buf0 done
        if (ht + 2 < 64) {
            stage(ht + 2, 0);
            __builtin_amdgcn_s_waitcnt(0x0F74);       // vmcnt(4)
        } else {
            __builtin_amdgcn_s_waitcnt(0x0F70);       // vmcnt(0)
        }
        __builtin_amdgcn_s_barrier();
        compute(K1, V1);
    }

    // ---- block-internal split-K combine + inline normalize ----
    __syncthreads();   // all K/V reads done; RAW reusable
    float* comb  = (float*)RAW;               // [64][68] f32, 17408 B
    float* combl = (float*)(RAW + 17408);     // 64 f32
    if (kh == 1) {
        #pragma unroll
        for (int g = 0; g < 2; g++) {
            const int lq = qh * 32 + g * 16 + ln;
            #pragma unroll
            for (int db = 0; db < 4; db++)
                *(f32x4*)&comb[lq * 68 + db * 16 + quad * 4] = accO[g][db];
            if (quad == 0) combl[lq] = accL[g][0];
        }
    }
    __syncthreads();
    if (kh == 0) {
        #pragma unroll
        for (int g = 0; g < 2; g++) {
            const int lq = qh * 32 + g * 16 + ln;
            const int qg = q0 + lq;
            // every lane's accL[g][0] holds l[q=ln] (rows identical for ones-A)
            float inv = 1.0f / (accL[g][0] + combl[lq]);
            float* op = out + (size_t)qg * 768 + h * 64 + quad * 4;
            #pragma unroll
            for (int db = 0; db < 4; db++) {
                f32x4 o = (accO[g][db] + *(const f32x4*)&comb[lq * 68 + db * 16 + quad * 4]);
                o *= inv;
                *(f32x4*)(op + db * 16) = o;
            }
        }
    }
}

// ---------------------------------------------------------------------------
extern "C" void kernel_launch(void* const* d_in, const int* in_sizes, int n_in,
                              void* d_out, int out_size, void* d_ws, size_t ws_size,
                              hipStream_t stream) {
    const float* x      = (const float*)d_in[0];
    const float* proj_w = (const float*)d_in[1];
    const float* proj_b = (const float*)d_in[2];
    const float* ln_g   = (const float*)d_in[3];
    const float* ln_b   = (const float*)d_in[4];
    const float* qkv_w  = (const float*)d_in[5];
    float* out = (float*)d_out;

    char* ws = (char*)d_ws;
    float*  tok_pre = (float*)(ws + 0);              // 12,582,912 B
    bf16_t* tok_b   = (bf16_t*)(ws + 12582912);      //  6,291,456 B
    bf16_t* qw_b    = (bf16_t*)(ws + 18874368);      //  3,538,944 B
    bf16_t* qbuf    = (bf16_t*)(ws + 22413312);      //  6,291,456 B
    bf16_t* kswz    = (bf16_t*)(ws + 28704768);      //  6,291,456 B
    bf16_t* vswz    = (bf16_t*)(ws + 34996224);      //  6,291,456 B (total ~41.3 MB)

    // patch tiles (by<64) + qkv_w cvt (by in [64,208))
    prep_kernel<<<dim3(12, 208), 256, 0, stream>>>(x, proj_w, proj_b, tok_pre, qkv_w, qw_b);
    ln_kernel<<<4096, 256, 0, stream>>>(tok_pre, ln_g, ln_b, tok_b);
    qkv_gemm<<<dim3(36, 32), 256, 0, stream>>>(tok_b, qw_b, qbuf, kswz, vswz);
    attn_full<<<dim3(64, 12), 256, 0, stream>>>(qbuf, kswz, vswz, out);
}

// Round 12
// 164.843 us; speedup vs baseline: 1.0685x; 1.0015x over previous
//
#include <hip/hip_runtime.h>
#include <hip/hip_bf16.h>

typedef __bf16 bf16_t;
typedef __attribute__((ext_vector_type(8))) __bf16 bf16x8;
typedef __attribute__((ext_vector_type(4))) __bf16 bf16x4;
typedef __attribute__((ext_vector_type(4))) float f32x4;
typedef __attribute__((ext_vector_type(4))) unsigned int uint4v;

#define QSCALE 0.1803368801111204f  /* 0.125 * log2(e) */

// async global->LDS, 16B per lane; LDS dst = wave-uniform base + lane*16
static __device__ inline void glds16(const bf16_t* g, bf16_t* l) {
    __builtin_amdgcn_global_load_lds(
        (__attribute__((address_space(1))) const void*)g,
        (__attribute__((address_space(3))) void*)l,
        16, 0, 0);
}

// raw hardware v_exp_f32 (input bounded — no libm range/denorm fixup needed)
static __device__ inline float hwexp2(float x) {
#if __has_builtin(__builtin_amdgcn_exp2f)
    return __builtin_amdgcn_exp2f(x);
#else
    float r;
    asm("v_exp_f32 %0, %1" : "=v"(r) : "v"(x));
    return r;
#endif
}

// pack two fp32 -> bf16x2 by truncation (top 16 bits), single v_perm_b32
static __device__ inline unsigned int pack_trunc(float lo, float hi) {
    return __builtin_amdgcn_perm(__builtin_bit_cast(unsigned int, hi),
                                 __builtin_bit_cast(unsigned int, lo),
                                 0x07060302u);
}

// ---------------------------------------------------------------------------
// Fused prep: patch-embed GEMM (by < 64) + qkv_w fp32->bf16 cvt (by >= 64).
// ---------------------------------------------------------------------------
__global__ __launch_bounds__(256) void prep_kernel(const float* __restrict__ x,
                                                   const float* __restrict__ pw,
                                                   const float* __restrict__ pb,
                                                   float* __restrict__ tok,
                                                   const float* __restrict__ qkv_w,
                                                   bf16_t* __restrict__ qw_b) {
    const int tid = threadIdx.x;

    if (blockIdx.y >= 64) {
        // ---- cvt slice: (by-64)*12 + bx in [0, 1728) ----
        int id = (blockIdx.y - 64) * 12 + blockIdx.x;
        int i = id * 256 + tid;                    // < 442368 always (exact)
        float4 v = ((const float4*)qkv_w)[i];
        bf16x4 o = {(bf16_t)v.x, (bf16_t)v.y, (bf16_t)v.z, (bf16_t)v.w};
        ((bf16x4*)qw_b)[i] = o;
        return;
    }

    const int bn = blockIdx.x;   // 12 embed tiles
    const int bm = blockIdx.y;   // 64 token tiles

    __shared__ bf16_t At[64][264];
    __shared__ bf16_t Bt[64][264];

    #pragma unroll
    for (int t = 0; t < 16; t++) {
        int linear = tid + t * 256;
        int ml = linear >> 6;
        int kv = (linear & 63) << 2;
        int n = bm * 64 + ml;
        int pr = n >> 6, pc = n & 63;
        int i = kv >> 4, j = kv & 15;
        float4 v = *(const float4*)(x + (pr * 16 + i) * 1024 + pc * 16 + j);
        bf16x4 o = {(bf16_t)v.x, (bf16_t)v.y, (bf16_t)v.z, (bf16_t)v.w};
        *(bf16x4*)(&At[ml][kv]) = o;
    }
    #pragma unroll
    for (int t = 0; t < 8; t++) {
        int linear = tid + t * 256;
        int nl = linear >> 5;
        int kv = (linear & 31) << 3;
        const float* src = pw + (size_t)(bn * 64 + nl) * 256 + kv;
        float4 v0 = *(const float4*)(src);
        float4 v1 = *(const float4*)(src + 4);
        bf16x8 o = {(bf16_t)v0.x, (bf16_t)v0.y, (bf16_t)v0.z, (bf16_t)v0.w,
                    (bf16_t)v1.x, (bf16_t)v1.y, (bf16_t)v1.z, (bf16_t)v1.w};
        *(bf16x8*)(&Bt[nl][kv]) = o;
    }
    __syncthreads();

    const int lane = tid & 63, wid = tid >> 6, ln = lane & 15, quad = lane >> 4;
    f32x4 acc[4];
    #pragma unroll
    for (int s = 0; s < 4; s++) acc[s] = {0.f, 0.f, 0.f, 0.f};

    #pragma unroll
    for (int kk = 0; kk < 8; kk++) {
        bf16x8 af = *(const bf16x8*)(&At[wid * 16 + ln][kk * 32 + quad * 8]);
        #pragma unroll
        for (int s = 0; s < 4; s++) {
            bf16x8 bfr = *(const bf16x8*)(&Bt[s * 16 + ln][kk * 32 + quad * 8]);
            acc[s] = __builtin_amdgcn_mfma_f32_16x16x32_bf16(af, bfr, acc[s], 0, 0, 0);
        }
    }

    #pragma unroll
    for (int s = 0; s < 4; s++) {
        int e = bn * 64 + s * 16 + ln;
        float bias = pb[e];
        #pragma unroll
        for (int r = 0; r < 4; r++) {
            int m = bm * 64 + wid * 16 + quad * 4 + r;
            tok[(size_t)m * 768 + e] = acc[s][r] + bias;
        }
    }
}

// ---------------------------------------------------------------------------
// LayerNorm per token (768), fp32 stats, bf16 out.
// ---------------------------------------------------------------------------
__global__ __launch_bounds__(256) void ln_kernel(const float* __restrict__ tok,
                                                 const float* __restrict__ g,
                                                 const float* __restrict__ b,
                                                 bf16_t* __restrict__ out) {
    const int n = blockIdx.x;
    const int tid = threadIdx.x;
    const float* row = tok + (size_t)n * 768;
    float x0 = row[tid], x1 = row[tid + 256], x2 = row[tid + 512];
    float s = x0 + x1 + x2;
    float s2 = x0 * x0 + x1 * x1 + x2 * x2;
    #pragma unroll
    for (int off = 32; off; off >>= 1) {
        s += __shfl_xor(s, off);
        s2 += __shfl_xor(s2, off);
    }
    __shared__ float ws1[4], ws2[4];
    int wid = tid >> 6;
    if ((tid & 63) == 0) { ws1[wid] = s; ws2[wid] = s2; }
    __syncthreads();
    s = ws1[0] + ws1[1] + ws1[2] + ws1[3];
    s2 = ws2[0] + ws2[1] + ws2[2] + ws2[3];
    float mu = s * (1.f / 768.f);
    float var = s2 * (1.f / 768.f) - mu * mu;
    float r = rsqrtf(var + 1e-6f);
    bf16_t* orow = out + (size_t)n * 768;
    orow[tid]       = (bf16_t)((x0 - mu) * r * g[tid]       + b[tid]);
    orow[tid + 256] = (bf16_t)((x1 - mu) * r * g[tid + 256] + b[tid + 256]);
    orow[tid + 512] = (bf16_t)((x2 - mu) * r * g[tid + 512] + b[tid + 512]);
}

// ---------------------------------------------------------------------------
// QKV GEMM: bn-fastest grid (36, 32), 128(M)x64(N) tile, BK=64, async dbuf
// glds16 staging with XOR-swizzled LDS. bn: 0..11 = q, 12..23 = k, 24..35 = v.
// (256,4): VGPR<=64 + AGPR 32 -> 128 regs/wave -> 4 waves/SIMD (v12 win).
// v13: LDS-staged epilogue — the block's output is a CONTIGUOUS 16KB global
// range for all sidx (q: (head*4096+bm*128)*64; k/v: (head*64+bm*2)*4096).
// Write acc into a 16KB LDS tile at the locally-permuted offset (cheap LDS
// scatter), then copy LDS->global coalesced (4 b128 stores/thread). Replaces
// 32 scattered 2B global stores/thread (9.4M total) + their address VALU.
// ---------------------------------------------------------------------------
__global__ __launch_bounds__(256, 4) void qkv_gemm(const bf16_t* __restrict__ tokb,
                                                   const bf16_t* __restrict__ wq,
                                                   bf16_t* __restrict__ qb,
                                                   bf16_t* __restrict__ kswz,
                                                   bf16_t* __restrict__ vswz) {
    const int bn = blockIdx.x;   // 36 n-tiles (64 cols = one head of q/k/v)
    const int bm = blockIdx.y;   // 32 m-tiles (128 tokens)
    const int tid = threadIdx.x;
    const int wid = tid >> 6, lane = tid & 63;
    const int ln = lane & 15, quad = lane >> 4;
    const int wm = wid & 1, wn = wid >> 1;

    __shared__ bf16_t Asw[2][8192];   // 128 rows x 8 chunks x 8 bf16
    __shared__ bf16_t Bsw[2][4096];   // 64 rows x 8 chunks

    f32x4 acc[4][2];
    #pragma unroll
    for (int sm = 0; sm < 4; sm++)
        #pragma unroll
        for (int sn = 0; sn < 2; sn++) acc[sm][sn] = {0.f, 0.f, 0.f, 0.f};

    // staging: per wave, A chunks [wid*256, +256) (4 issues), B [wid*128, +128) (2)
    auto stage = [&](int kb0, int buf) {
        #pragma unroll
        for (int i = 0; i < 4; i++) {
            int L = wid * 256 + i * 64 + lane;
            int r = L >> 3, c = L & 7;
            int gc = c ^ (r & 7);
            glds16(tokb + (size_t)(bm * 128 + r) * 768 + kb0 + gc * 8,
                   Asw[buf] + (wid * 256 + i * 64) * 8);
        }
        #pragma unroll
        for (int i = 0; i < 2; i++) {
            int L = wid * 128 + i * 64 + lane;
            int r = L >> 3, c = L & 7;
            int gc = c ^ (r & 7);
            glds16(wq + (size_t)(bn * 64 + r) * 768 + kb0 + gc * 8,
                   Bsw[buf] + (wid * 128 + i * 64) * 8);
        }
    };

    auto compute = [&](const bf16_t* Ab, const bf16_t* Bb) {
        #pragma unroll
        for (int kk = 0; kk < 2; kk++) {
            const int c = (kk * 4 + quad) ^ (ln & 7);
            bf16x8 af[4], bfr[2];
            #pragma unroll
            for (int sm = 0; sm < 4; sm++) {
                int row = wm * 64 + sm * 16 + ln;
                af[sm] = *(const bf16x8*)(Ab + (row * 8 + c) * 8);
            }
            #pragma unroll
            for (int sn = 0; sn < 2; sn++) {
                int row = wn * 32 + sn * 16 + ln;
                bfr[sn] = *(const bf16x8*)(Bb + (row * 8 + c) * 8);
            }
            #pragma unroll
            for (int sm = 0; sm < 4; sm++)
                #pragma unroll
                for (int sn = 0; sn < 2; sn++)
                    acc[sm][sn] = __builtin_amdgcn_mfma_f32_16x16x32_bf16(af[sm], bfr[sn], acc[sm][sn], 0, 0, 0);
        }
    };

    stage(0, 0);

    for (int s = 0; s < 12; s += 2) {
        __builtin_amdgcn_s_barrier();                 // prev reads of buf1 done
        stage((s + 1) * 64, 1);
        __builtin_amdgcn_s_waitcnt(0x0F76);           // vmcnt(6): buf0 resident
        __builtin_amdgcn_s_barrier();
        compute(Asw[0], Bsw[0]);
        __builtin_amdgcn_s_barrier();                 // prev reads of buf0 done
        if (s + 2 < 12) {
            stage((s + 2) * 64, 0);
            __builtin_amdgcn_s_waitcnt(0x0F76);       // vmcnt(6)
        } else {
            __builtin_amdgcn_s_waitcnt(0x0F70);       // vmcnt(0)
        }
        __builtin_amdgcn_s_barrier();
        compute(Asw[1], Bsw[1]);
    }

    // ---- epilogue: permuted scatter into 16KB LDS tile, coalesced copy out
    __syncthreads();                       // all staging-buffer reads done
    bf16_t* otile = Asw[0];                // 8192 bf16 = 16 KB scratch
    const int sidx = bn / 12;              // 0=q 1=k 2=v (block-uniform)
    const int head = bn % 12;
    #pragma unroll
    for (int sn = 0; sn < 2; sn++) {
        int dc = wn * 32 + sn * 16 + ln;   // 0..63 within head
        #pragma unroll
        for (int sm = 0; sm < 4; sm++) {
            #pragma unroll
            for (int r = 0; r < 4; r++) {
                int ml = wm * 64 + sm * 16 + quad * 4 + r;   // local token 0..127
                float v = acc[sm][sn][r];
                int loc;
                bf16_t val;
                if (sidx == 0) {
                    val = (bf16_t)(v * QSCALE);
                    loc = ml * 64 + dc;
                } else if (sidx == 1) {
                    val = (bf16_t)v;
                    int ktl = ml >> 6, sb = (ml >> 4) & 3, lnk = ml & 15;
                    int half = dc >> 5, quadk = (dc >> 3) & 3, j = dc & 7;
                    int l = quadk * 16 + lnk;
                    loc = ktl * 4096 + sb * 1024 + half * 512 + l * 8 + j;
                } else {
                    val = (bf16_t)v;
                    int ktl = ml >> 6, keyl = ml & 63;
                    int sblk = keyl >> 4;
                    int mm = sblk >> 1, tb = sblk & 1;
                    int w16 = keyl & 15, qv = w16 >> 2, jj = w16 & 3;
                    int jp = tb * 4 + jj;
                    int db = dc >> 4, lnv = dc & 15;
                    int l = qv * 16 + lnv;
                    loc = ktl * 4096 + ((mm * 4 + db) * 64 + l) * 8 + jp;
                }
                otile[loc] = val;
            }
        }
    }
    __syncthreads();
    bf16_t* dst = (sidx == 0) ? qb   + ((size_t)(head * 4096 + bm * 128)) * 64
                : (sidx == 1) ? kswz + ((size_t)(head * 64 + bm * 2)) * 4096
                              : vswz + ((size_t)(head * 64 + bm * 2)) * 4096;
    #pragma unroll
    for (int t = 0; t < 4; t++) {
        int off = (tid + t * 256) * 8;     // 8 bf16 = 16B per store
        *(bf16x8*)(dst + off) = *(const bf16x8*)(otile + off);
    }
}

// ---------------------------------------------------------------------------
// Attention v12 core (unchanged): 32q/wave, 64V/40A regs (4-wave/SIMD step),
// half-tile glds dbuf, kh split-K pair, inline normalize.
// ---------------------------------------------------------------------------
__global__ __launch_bounds__(256, 4) void attn_full(const bf16_t* __restrict__ qbuf,
                                                    const bf16_t* __restrict__ kswz,
                                                    const bf16_t* __restrict__ vswz,
                                                    float* __restrict__ out) {
    const int h = blockIdx.y;
    const int tid = threadIdx.x;
    const int wid = tid >> 6;           // 0..3
    const int lane = tid & 63;
    const int ln = lane & 15, quad = lane >> 4;
    const int qh = wid & 1;             // which 32-query half of the 64q block
    const int kh = wid >> 1;            // which 2048-key half (block split-K)
    const int q0 = blockIdx.x * 64;

    // staging: K [2 kh][2 buf][2048] at 0, V same at +16384 (32KB total);
    // combine view after syncthreads: [64][68] f32 + l[64] = 17.7KB (fits).
    __shared__ __align__(16) char RAW[32768];
    bf16_t* Kst = (bf16_t*)RAW;
    bf16_t* Vst = (bf16_t*)(RAW + 16384);

    // Q B-frags for this wave's two 16-query groups (32 queries/wave)
    bf16x8 qf[2][2];
    #pragma unroll
    for (int g = 0; g < 2; g++) {
        const int q0g = q0 + qh * 32 + g * 16;
        const bf16_t* qrow = qbuf + ((size_t)h * 4096 + q0g + ln) * 64;
        qf[g][0] = *(const bf16x8*)(qrow + quad * 8);
        qf[g][1] = *(const bf16x8*)(qrow + 32 + quad * 8);
    }

    // all-ones A fragment for the l row-sum MFMA
    bf16x8 ones;
    #pragma unroll
    for (int i = 0; i < 8; i++) ones[i] = (bf16_t)1.0f;

    // this pair's 32-tile (= 64 half-tile) key sub-range
    const bf16_t* kg = kswz + (size_t)h * 64 * 4096 + (size_t)(kh * 32) * 4096;
    const bf16_t* vg = vswz + (size_t)h * 64 * 4096 + (size_t)(kh * 32) * 4096;

    f32x4 accO[2][4];
    f32x4 accL[2];
    #pragma unroll
    for (int g = 0; g < 2; g++) {
        accL[g] = {0.f, 0.f, 0.f, 0.f};
        #pragma unroll
        for (int d = 0; d < 4; d++) accO[g][d] = {0.f, 0.f, 0.f, 0.f};
    }

    // stage one 4KB K + 4KB V half-tile (32 keys) per kh pair; the pair's
    // two waves (qh) each cover half: 2 K + 2 V glds16 per wave
    auto stage = [&](int ht, int buf) {
        const bf16_t* kt_g = kg + (size_t)ht * 2048;
        const bf16_t* vt_g = vg + (size_t)ht * 2048;
        bf16_t* kl = Kst + (kh * 2 + buf) * 2048 + qh * 1024;
        bf16_t* vl = Vst + (kh * 2 + buf) * 2048 + qh * 1024;
        #pragma unroll
        for (int i = 0; i < 2; i++) {
            glds16(kt_g + qh * 1024 + i * 512 + lane * 8, kl + i * 512);
            glds16(vt_g + qh * 1024 + i * 512 + lane * 8, vl + i * 512);
        }
    };

    // one 32-key half-tile; minimal-liveness sequencing: each S-tile's exp
    // + pack is consumed before the next S-tile is produced.
    auto compute = [&](const bf16_t* Kb, const bf16_t* Vb) {
        bf16x8 vf0 = *(const bf16x8*)(Vb + 0 * 512 + lane * 8);
        bf16x8 vf1 = *(const bf16x8*)(Vb + 1 * 512 + lane * 8);
        bf16x8 vf2 = *(const bf16x8*)(Vb + 2 * 512 + lane * 8);
        bf16x8 vf3 = *(const bf16x8*)(Vb + 3 * 512 + lane * 8);
        bf16x8 ka0 = *(const bf16x8*)(Kb + lane * 8);
        bf16x8 ka1 = *(const bf16x8*)(Kb + 512 + lane * 8);
        bf16x8 kb0 = *(const bf16x8*)(Kb + 1024 + lane * 8);
        bf16x8 kb1 = *(const bf16x8*)(Kb + 1536 + lane * 8);
        #pragma unroll
        for (int g = 0; g < 2; g++) {
            f32x4 z = {0.f, 0.f, 0.f, 0.f};
            f32x4 SA = __builtin_amdgcn_mfma_f32_16x16x32_bf16(ka0, qf[g][0], z, 0, 0, 0);
            SA = __builtin_amdgcn_mfma_f32_16x16x32_bf16(ka1, qf[g][1], SA, 0, 0, 0);
            unsigned int u0 = pack_trunc(hwexp2(SA[0]), hwexp2(SA[1]));
            unsigned int u1 = pack_trunc(hwexp2(SA[2]), hwexp2(SA[3]));
            f32x4 SB = __builtin_amdgcn_mfma_f32_16x16x32_bf16(kb0, qf[g][0], z, 0, 0, 0);
            SB = __builtin_amdgcn_mfma_f32_16x16x32_bf16(kb1, qf[g][1], SB, 0, 0, 0);
            unsigned int u2 = pack_trunc(hwexp2(SB[0]), hwexp2(SB[1]));
            unsigned int u3 = pack_trunc(hwexp2(SB[2]), hwexp2(SB[3]));
            uint4v u = {u0, u1, u2, u3};
            bf16x8 pb = __builtin_bit_cast(bf16x8, u);
            accL[g] = __builtin_amdgcn_mfma_f32_16x16x32_bf16(ones, pb, accL[g], 0, 0, 0);
            accO[g][0] = __builtin_amdgcn_mfma_f32_16x16x32_bf16(vf0, pb, accO[g][0], 0, 0, 0);
            accO[g][1] = __builtin_amdgcn_mfma_f32_16x16x32_bf16(vf1, pb, accO[g][1], 0, 0, 0);
            accO[g][2] = __builtin_amdgcn_mfma_f32_16x16x32_bf16(vf2, pb, accO[g][2], 0, 0, 0);
            accO[g][3] = __builtin_amdgcn_mfma_f32_16x16x32_bf16(vf3, pb, accO[g][3], 0, 0, 0);
        }
    };

    stage(0, 0);

    const bf16_t* K0 = Kst + (kh * 2 + 0) * 2048;
    const bf16_t* V0 = Vst + (kh * 2 + 0) * 2048;
    const bf16_t* K1 = Kst + (kh * 2 + 1) * 2048;
    const bf16_t* V1 = Vst + (kh * 2 + 1) * 2048;

    for (int ht = 0; ht < 64; ht += 2) {
        __builtin_amdgcn_s_barrier();                 // prev reads of buf1 done
        stage(ht + 1, 1);
        __builtin_amdgcn_s_waitcnt(0x0F74);           // vmcnt(4): half-tile ht resident
        __builtin_amdgcn_s_barrier();
        compute(K0, V0);
        __builtin_amdgcn_s_barrier();                 // prev reads of buf0 done
        if (ht + 2 < 64) {
            stage(ht + 2, 0);
            __builtin_amdgcn_s_waitcnt(0x0F74);       // vmcnt(4)
        } else {
            __builtin_amdgcn_s_waitcnt(0x0F70);       // vmcnt(0)
        }
        __builtin_amdgcn_s_barrier();
        compute(K1, V1);
    }

    // ---- block-internal split-K combine + inline normalize ----
    __syncthreads();   // all K/V reads done; RAW reusable
    float* comb  = (float*)RAW;               // [64][68] f32, 17408 B
    float* combl = (float*)(RAW + 17408);     // 64 f32
    if (kh == 1) {
        #pragma unroll
        for (int g = 0; g < 2; g++) {
            const int lq = qh * 32 + g * 16 + ln;
            #pragma unroll
            for (int db = 0; db < 4; db++)
                *(f32x4*)&comb[lq * 68 + db * 16 + quad * 4] = accO[g][db];
            if (quad == 0) combl[lq] = accL[g][0];
        }
    }
    __syncthreads();
    if (kh == 0) {
        #pragma unroll
        for (int g = 0; g < 2; g++) {
            const int lq = qh * 32 + g * 16 + ln;
            const int qg = q0 + lq;
            // every lane's accL[g][0] holds l[q=ln] (rows identical for ones-A)
            float inv = 1.0f / (accL[g][0] + combl[lq]);
            float* op = out + (size_t)qg * 768 + h * 64 + quad * 4;
            #pragma unroll
            for (int db = 0; db < 4; db++) {
                f32x4 o = (accO[g][db] + *(const f32x4*)&comb[lq * 68 + db * 16 + quad * 4]);
                o *= inv;
                *(f32x4*)(op + db * 16) = o;
            }
        }
    }
}

// ---------------------------------------------------------------------------
extern "C" void kernel_launch(void* const* d_in, const int* in_sizes, int n_in,
                              void* d_out, int out_size, void* d_ws, size_t ws_size,
                              hipStream_t stream) {
    const float* x      = (const float*)d_in[0];
    const float* proj_w = (const float*)d_in[1];
    const float* proj_b = (const float*)d_in[2];
    const float* ln_g   = (const float*)d_in[3];
    const float* ln_b   = (const float*)d_in[4];
    const float* qkv_w  = (const float*)d_in[5];
    float* out = (float*)d_out;

    char* ws = (char*)d_ws;
    float*  tok_pre = (float*)(ws + 0);              // 12,582,912 B
    bf16_t* tok_b   = (bf16_t*)(ws + 12582912);      //  6,291,456 B
    bf16_t* qw_b    = (bf16_t*)(ws + 18874368);      //  3,538,944 B
    bf16_t* qbuf    = (bf16_t*)(ws + 22413312);      //  6,291,456 B
    bf16_t* kswz    = (bf16_t*)(ws + 28704768);      //  6,291,456 B
    bf16_t* vswz    = (bf16_t*)(ws + 34996224);      //  6,291,456 B (total ~41.3 MB)

    // patch tiles (by<64) + qkv_w cvt (by in [64,208))
    prep_kernel<<<dim3(12, 208), 256, 0, stream>>>(x, proj_w, proj_b, tok_pre, qkv_w, qw_b);
    ln_kernel<<<4096, 256, 0, stream>>>(tok_pre, ln_g, ln_b, tok_b);
    qkv_gemm<<<dim3(36, 32), 256, 0, stream>>>(tok_b, qw_b, qbuf, kswz, vswz);
    attn_full<<<dim3(64, 12), 256, 0, stream>>>(qbuf, kswz, vswz, out);
}